// Round 1
// 873.046 us; speedup vs baseline: 1.1776x; 1.1776x over previous
//
#include <hip/hip_runtime.h>
#include <stdint.h>
#include <stddef.h>

// NASCell fused: new_m,new_c = gates(x@Wx, m_prev@Wm, c_prev)
// B=8192, I=H=1024, 8H=8192. Outputs fp32: new_m at [0,8.4M), new_c at [8.4M,16.8M).
//
// V2 structure (this round): move ALL fp32->fp16 hi/lo splitting out of the
// hot loop into pre-kernels writing d_ws (128 MB needed; legacy fallback kept):
//   prep_b : weights -> pre-split/packed/swizzled LDS tile images [kt][hblk]
//   split_a: x,m_prev -> xh/xl/mh/ml fp16 row-major
// Main kernel: global_load_lds (16B) double-buffered one-tile-ahead prefetch
// for B (no VGPR staging, no ds_write, no split VALU), direct half8 register
// loads for A. Arithmetic identical to V1 (3-pass hh/hl/lh fp16 MFMA, fp32
// accum) -> identical accuracy.
// LDS tile swizzle: short pos = mat*4096 + g*512 + n*32 + (k ^ (((n>>1)&3)<<3))
// -> ds_read_b128 conflicts drop from 8-way to 2-way (free).

typedef _Float16 half8 __attribute__((ext_vector_type(8)));
typedef float f32x4 __attribute__((ext_vector_type(4)));
typedef float float4v __attribute__((ext_vector_type(4)));
typedef unsigned int u32;
typedef u32 u32x4 __attribute__((ext_vector_type(4)));

__device__ __forceinline__ float fsig(float x) { return 1.0f / (1.0f + __expf(-x)); }
__device__ __forceinline__ float ftanh(float x) { return 2.0f * fsig(2.0f * x) - 1.0f; }
__device__ __forceinline__ u32 packh(_Float16 a, _Float16 b) {
  union { u32 u; _Float16 h[2]; } p;
  p.h[0] = a; p.h[1] = b; return p.u;
}

__device__ __forceinline__ void gload16(const void* g, void* l) {
  __builtin_amdgcn_global_load_lds(
      (const __attribute__((address_space(1))) void*)g,
      (__attribute__((address_space(3))) void*)l, 16, 0, 0);
}

// ---------------------------------------------------------------------------
// prep_b: build per-(kt,hblk) 32KB LDS tile images of the weights.
// Tile layout (u32 words): [0,2048)=hi w_inputs, [2048,4096)=hi w_m,
//                          [4096,6144)=lo w_inputs, [6144,8192)=lo w_m.
// Within a mat region: g*256 + n*16 + word, word w holds shorts k=2*(w^kx4),+1
// with kx4 = ((n>>1)&3)<<2  (i.e. short pos = k ^ (((n>>1)&3)<<3)).
// ---------------------------------------------------------------------------
__global__ __launch_bounds__(256) void prep_b(
    const float* __restrict__ w_inputs, const float* __restrict__ w_m,
    u32* __restrict__ wsB) {
  const int kt = blockIdx.x;    // 0..31
  const int hblk = blockIdx.y;  // 0..63
  const int tid = threadIdx.x;
  const int n = tid & 15;
  const int g = (tid >> 4) & 7;
  const int mat = tid >> 7;
  const float* w = mat ? w_m : w_inputs;
  const float* src = w + (size_t)kt * 32 * 8192 + (size_t)g * 1024 + hblk * 16 + n;
  const int kx4 = ((n >> 1) & 3) << 2;
  u32 hw[16], lw[16];
#pragma unroll
  for (int k2 = 0; k2 < 16; ++k2) {           // read in k order (coalesced rows)
    const float v0 = src[(size_t)(2 * k2) * 8192];
    const float v1 = src[(size_t)(2 * k2 + 1) * 8192];
    const _Float16 h0 = (_Float16)v0, h1 = (_Float16)v1;
    hw[k2 ^ kx4] = packh(h0, h1);
    lw[k2 ^ kx4] = packh((_Float16)(v0 - (float)h0), (_Float16)(v1 - (float)h1));
  }
  u32* dhi = wsB + ((size_t)kt * 64 + hblk) * 8192 + mat * 2048 + g * 256 + n * 16;
  u32* dlo = dhi + 4096;
#pragma unroll
  for (int t4 = 0; t4 < 4; ++t4) {
    u32x4 a = {hw[t4 * 4], hw[t4 * 4 + 1], hw[t4 * 4 + 2], hw[t4 * 4 + 3]};
    *(u32x4*)(dhi + t4 * 4) = a;
    u32x4 b = {lw[t4 * 4], lw[t4 * 4 + 1], lw[t4 * 4 + 2], lw[t4 * 4 + 3]};
    *(u32x4*)(dlo + t4 * 4) = b;
  }
}

// ---------------------------------------------------------------------------
// split_a: elementwise fp32 -> (hi fp16, lo fp16). 8 elems/thread.
// ---------------------------------------------------------------------------
__global__ __launch_bounds__(256) void split_a(
    const float4v* __restrict__ in, half8* __restrict__ hi, half8* __restrict__ lo) {
  const size_t idx = (size_t)blockIdx.x * 256 + threadIdx.x;  // 1,048,576 total
  const float4v a = in[idx * 2];
  const float4v b = in[idx * 2 + 1];
  half8 h, l;
#pragma unroll
  for (int j = 0; j < 4; ++j) {
    const float v = a[j]; const _Float16 hv = (_Float16)v;
    h[j] = hv; l[j] = (_Float16)(v - (float)hv);
  }
#pragma unroll
  for (int j = 0; j < 4; ++j) {
    const float v = b[j]; const _Float16 hv = (_Float16)v;
    h[4 + j] = hv; l[4 + j] = (_Float16)(v - (float)hv);
  }
  hi[idx] = h; lo[idx] = l;
}

// ---------------------------------------------------------------------------
// Main kernel (fast path): 256 rows x 16 h-cols per block, 16x16x32 f16 MFMA,
// 3-pass two-term split, gates j!=3 concat-K accumulate, gate 3 separate.
// B staged via global_load_lds into double-buffered LDS (2 x 32KB).
// One __syncthreads per kt (implicit vmcnt(0) drains previous prefetch).
// ---------------------------------------------------------------------------
__global__ __launch_bounds__(256, 2) void nascell_fast(
    const _Float16* __restrict__ xh_g, const _Float16* __restrict__ xl_g,
    const _Float16* __restrict__ mh_g, const _Float16* __restrict__ ml_g,
    const u32* __restrict__ wsB,
    const float* __restrict__ c_prev,
    float* __restrict__ out) {
  __shared__ short lds[32768];  // 2 buffers x 32 KB
  const int tid = threadIdx.x;
  const int wid = tid >> 6;
  const int lane = tid & 63;
  const int row0 = blockIdx.y * 256;
  const int hblk = blockIdx.x;
  const int m16 = lane & 15;
  const int q = lane >> 4;
  const int qsw = (q ^ ((m16 >> 1) & 3)) * 8;  // swizzled k-chunk (shorts)

  const size_t arow = (size_t)(row0 + wid * 64 + m16);
  const _Float16* xhb = xh_g + arow * 1024 + q * 8;
  const _Float16* xlb = xl_g + arow * 1024 + q * 8;
  const _Float16* mhb = mh_g + arow * 1024 + q * 8;
  const _Float16* mlb = ml_g + arow * 1024 + q * 8;

  // per-lane staging source (16B/lane, contiguous 1KB per wave-instr)
  const char* wsb = (const char*)wsB + (size_t)hblk * 32768 + wid * 8192 + lane * 16;
  char* ldsb0 = (char*)lds + wid * 8192;  // wave-uniform LDS dest base

  f32x4 acc[4][9];
#pragma unroll
  for (int r = 0; r < 4; ++r)
#pragma unroll
    for (int gg = 0; gg < 9; ++gg) acc[r][gg] = (f32x4)0.0f;

  // prologue: stage tile kt=0 into buf0
#pragma unroll
  for (int i = 0; i < 8; ++i) gload16(wsb + i * 1024, ldsb0 + i * 1024);

  for (int kt = 0; kt < 32; ++kt) {
    __syncthreads();  // waits vmcnt(0): prefetch(kt) landed; syncs all waves

    // A fragment loads for kt (already-split fp16, 16B each)
    half8 axh[4], axl[4], amh[4], aml[4];
#pragma unroll
    for (int r = 0; r < 4; ++r) {
      axh[r] = *(const half8*)(xhb + (size_t)r * 16384 + kt * 32);
      axl[r] = *(const half8*)(xlb + (size_t)r * 16384 + kt * 32);
      amh[r] = *(const half8*)(mhb + (size_t)r * 16384 + kt * 32);
      aml[r] = *(const half8*)(mlb + (size_t)r * 16384 + kt * 32);
    }
    // keep A loads older than the prefetch: compiler waits for A at vmcnt(8),
    // which never drains the prefetch queue.
    __builtin_amdgcn_sched_barrier(0);
    if (kt < 31) {
      const char* src = wsb + (size_t)(kt + 1) * 2097152;  // 64 tiles * 32KB
      char* dst = (char*)lds + ((kt + 1) & 1) * 32768 + wid * 8192;
#pragma unroll
      for (int i = 0; i < 8; ++i) gload16(src + i * 1024, dst + i * 1024);
    }
    __builtin_amdgcn_sched_barrier(0);

    const short* bb = lds + (kt & 1) * 16384;

    // ---- x-pass: acc += xh*Bh + xh*Bl + xl*Bh (w_inputs region, mat 0) ----
#pragma unroll
    for (int c = 0; c < 8; ++c) {
      const int bo = c * 512 + m16 * 32 + qsw;
      const half8 bxh = *(const half8*)(bb + bo);
      const half8 bxl = *(const half8*)(bb + 8192 + bo);
#pragma unroll
      for (int r = 0; r < 4; ++r) {
        f32x4 t = acc[r][c];
        t = __builtin_amdgcn_mfma_f32_16x16x32_f16(axh[r], bxh, t, 0, 0, 0);
        t = __builtin_amdgcn_mfma_f32_16x16x32_f16(axh[r], bxl, t, 0, 0, 0);
        t = __builtin_amdgcn_mfma_f32_16x16x32_f16(axl[r], bxh, t, 0, 0, 0);
        acc[r][c] = t;
      }
    }

    // ---- m-pass: gate c!=3 adds into acc[r][c]; gate 3 -> acc[r][8] ----
#pragma unroll
    for (int c = 0; c < 8; ++c) {
      const int bo = 4096 + c * 512 + m16 * 32 + qsw;  // mat 1 region
      const half8 bmh = *(const half8*)(bb + bo);
      const half8 bml = *(const half8*)(bb + 8192 + bo);
      const int tgt = (c == 3) ? 8 : c;
#pragma unroll
      for (int r = 0; r < 4; ++r) {
        f32x4 t = acc[r][tgt];
        t = __builtin_amdgcn_mfma_f32_16x16x32_f16(amh[r], bmh, t, 0, 0, 0);
        t = __builtin_amdgcn_mfma_f32_16x16x32_f16(amh[r], bml, t, 0, 0, 0);
        t = __builtin_amdgcn_mfma_f32_16x16x32_f16(aml[r], bmh, t, 0, 0, 0);
        acc[r][tgt] = t;
      }
    }
  }

  // ---- epilogue: per-lane gate combine, fp32 outputs (unchanged) ----
  float* out_m = out;
  float* out_c = out + (size_t)8192 * 1024;
  const int h = hblk * 16 + m16;
#pragma unroll
  for (int r = 0; r < 4; ++r) {
#pragma unroll
    for (int i = 0; i < 4; ++i) {
      const int grow = row0 + wid * 64 + r * 16 + q * 4 + i;
      const float p0 = acc[r][0][i], p1 = acc[r][1][i], p2 = acc[r][2][i];
      const float x3 = acc[r][3][i], p4 = acc[r][4][i], p5 = acc[r][5][i];
      const float p6 = acc[r][6][i], p7 = acc[r][7][i], m3 = acc[r][8][i];
      const float cp = c_prev[(size_t)grow * 1024 + h];
      float l1_0 = fsig(p0);
      float l1_1 = fmaxf(p1, 0.0f);
      float l1_2 = fsig(p2);
      float l1_3 = fmaxf(x3 * m3, 0.0f);
      float l1_4 = ftanh(p4);
      float l1_5 = fsig(p5);
      float l1_6 = ftanh(p6);
      float l1_7 = fsig(p7);
      float l2_0 = ftanh(l1_0 * l1_1);
      float l2_1 = ftanh(l1_2 + l1_3);
      float l2_2 = ftanh(l1_4 * l1_5);
      float l2_3 = fsig(l1_6 + l1_7);
      float l2_0b = ftanh(l2_0 + cp);
      float nc = l2_0b * l2_1;
      float l3_1 = ftanh(l2_2 + l2_3);
      float nm = ftanh(nc * l3_1);
      out_m[(size_t)grow * 1024 + h] = nm;
      out_c[(size_t)grow * 1024 + h] = nc;
    }
  }
}

// ---------------------------------------------------------------------------
// Legacy kernel (V1) — fallback when ws_size < 128 MB. Unchanged.
// ---------------------------------------------------------------------------
__global__ __launch_bounds__(256, 2) void nascell_main(
    const float* __restrict__ x,
    const float* __restrict__ m_prev,
    const float* __restrict__ c_prev,
    const float* __restrict__ w_inputs,
    const float* __restrict__ w_m,
    float* __restrict__ out) {
  __shared__ short lds[17408];
  const int tid = threadIdx.x;
  const int wid = tid >> 6;
  const int lane = tid & 63;
  const int row0 = blockIdx.y * 256;
  const int h0 = blockIdx.x * 16;
  const int m16 = lane & 15;
  const int q = lane >> 4;

  const int bmat = tid >> 7;
  const int bg = (tid >> 4) & 7;
  const int bkp = (tid & 15) * 2;
  const float* wsrc = bmat ? w_m : w_inputs;
  const float* wrow_base = wsrc + (size_t)bkp * 8192 + (size_t)bg * 1024 + (size_t)h0;
  short* bh = lds + bmat * 4352 + bg * 544 + (bkp ^ ((bg & 3) << 3));
  short* bl = bh + 8704;

  const float* axp[4];
  const float* amp[4];
#pragma unroll
  for (int r = 0; r < 4; ++r) {
    const size_t arow = (size_t)(row0 + wid * 64 + r * 16 + m16);
    axp[r] = x + arow * 1024 + q * 8;
    amp[r] = m_prev + arow * 1024 + q * 8;
  }

  f32x4 acc[4][9];
#pragma unroll
  for (int r = 0; r < 4; ++r)
#pragma unroll
    for (int gg = 0; gg < 9; ++gg) acc[r][gg] = (f32x4)0.0f;

  for (int kt = 0; kt < 32; ++kt) {
    const float* wr = wrow_base + (size_t)kt * 32 * 8192;
    float4v b0 = *(const float4v*)(wr);
    float4v b1 = *(const float4v*)(wr + 4);
    float4v b2 = *(const float4v*)(wr + 8);
    float4v b3 = *(const float4v*)(wr + 12);
    float4v d0 = *(const float4v*)(wr + 8192);
    float4v d1 = *(const float4v*)(wr + 8196);
    float4v d2 = *(const float4v*)(wr + 8200);
    float4v d3 = *(const float4v*)(wr + 8204);

    float4v xa[4][2];
#pragma unroll
    for (int r = 0; r < 4; ++r) {
      xa[r][0] = *(const float4v*)(axp[r] + kt * 32);
      xa[r][1] = *(const float4v*)(axp[r] + kt * 32 + 4);
    }

    __syncthreads();

#pragma unroll
    for (int n = 0; n < 16; ++n) {
      const float r0 = (n < 4 ? b0[n & 3] : n < 8 ? b1[n & 3] : n < 12 ? b2[n & 3] : b3[n & 3]);
      const float r1 = (n < 4 ? d0[n & 3] : n < 8 ? d1[n & 3] : n < 12 ? d2[n & 3] : d3[n & 3]);
      const _Float16 h0v = (_Float16)r0;
      const _Float16 h1v = (_Float16)r1;
      *(u32*)(bh + n * 32) = packh(h0v, h1v);
      const _Float16 l0v = (_Float16)(r0 - (float)h0v);
      const _Float16 l1v = (_Float16)(r1 - (float)h1v);
      *(u32*)(bl + n * 32) = packh(l0v, l1v);
    }

    half8 axh[4], axl[4];
#pragma unroll
    for (int r = 0; r < 4; ++r)
#pragma unroll
      for (int j = 0; j < 8; ++j) {
        const float v = xa[r][j >> 2][j & 3];
        const _Float16 hv = (_Float16)v;
        axh[r][j] = hv;
        axl[r][j] = (_Float16)(v - (float)hv);
      }

    __syncthreads();

    float4v ma[4][2];
#pragma unroll
    for (int r = 0; r < 4; ++r) {
      ma[r][0] = *(const float4v*)(amp[r] + kt * 32);
      ma[r][1] = *(const float4v*)(amp[r] + kt * 32 + 4);
    }

#pragma unroll
    for (int c = 0; c < 8; ++c) {
      const int qs = (q ^ (c & 3)) * 8;
      const int bo = c * 544 + m16 * 32 + qs;
      half8 bxh = *(const half8*)(lds + bo);
      half8 bxl = *(const half8*)(lds + 8704 + bo);
#pragma unroll
      for (int r = 0; r < 4; ++r) {
        f32x4 t = acc[r][c];
        t = __builtin_amdgcn_mfma_f32_16x16x32_f16(axh[r], bxh, t, 0, 0, 0);
        t = __builtin_amdgcn_mfma_f32_16x16x32_f16(axh[r], bxl, t, 0, 0, 0);
        t = __builtin_amdgcn_mfma_f32_16x16x32_f16(axl[r], bxh, t, 0, 0, 0);
        acc[r][c] = t;
      }
    }

    half8 amh[4], aml[4];
#pragma unroll
    for (int r = 0; r < 4; ++r)
#pragma unroll
      for (int j = 0; j < 8; ++j) {
        const float v = ma[r][j >> 2][j & 3];
        const _Float16 hv = (_Float16)v;
        amh[r][j] = hv;
        aml[r][j] = (_Float16)(v - (float)hv);
      }

#pragma unroll
    for (int c = 0; c < 8; ++c) {
      const int qs = (q ^ (c & 3)) * 8;
      const int bo = 4352 + c * 544 + m16 * 32 + qs;
      half8 bmh = *(const half8*)(lds + bo);
      half8 bml = *(const half8*)(lds + 8704 + bo);
      const int tgt = (c == 3) ? 8 : c;
#pragma unroll
      for (int r = 0; r < 4; ++r) {
        f32x4 t = acc[r][tgt];
        t = __builtin_amdgcn_mfma_f32_16x16x32_f16(amh[r], bmh, t, 0, 0, 0);
        t = __builtin_amdgcn_mfma_f32_16x16x32_f16(amh[r], bml, t, 0, 0, 0);
        t = __builtin_amdgcn_mfma_f32_16x16x32_f16(aml[r], bmh, t, 0, 0, 0);
        acc[r][tgt] = t;
      }
    }
  }

  float* out_m = out;
  float* out_c = out + (size_t)8192 * 1024;
  const int h = h0 + m16;
#pragma unroll
  for (int r = 0; r < 4; ++r) {
#pragma unroll
    for (int i = 0; i < 4; ++i) {
      const int grow = row0 + wid * 64 + r * 16 + q * 4 + i;
      const float p0 = acc[r][0][i], p1 = acc[r][1][i], p2 = acc[r][2][i];
      const float x3 = acc[r][3][i], p4 = acc[r][4][i], p5 = acc[r][5][i];
      const float p6 = acc[r][6][i], p7 = acc[r][7][i], m3 = acc[r][8][i];
      const float cp = c_prev[(size_t)grow * 1024 + h];
      float l1_0 = fsig(p0);
      float l1_1 = fmaxf(p1, 0.0f);
      float l1_2 = fsig(p2);
      float l1_3 = fmaxf(x3 * m3, 0.0f);
      float l1_4 = ftanh(p4);
      float l1_5 = fsig(p5);
      float l1_6 = ftanh(p6);
      float l1_7 = fsig(p7);
      float l2_0 = ftanh(l1_0 * l1_1);
      float l2_1 = ftanh(l1_2 + l1_3);
      float l2_2 = ftanh(l1_4 * l1_5);
      float l2_3 = fsig(l1_6 + l1_7);
      float l2_0b = ftanh(l2_0 + cp);
      float nc = l2_0b * l2_1;
      float l3_1 = ftanh(l2_2 + l2_3);
      float nm = ftanh(nc * l3_1);
      out_m[(size_t)grow * 1024 + h] = nm;
      out_c[(size_t)grow * 1024 + h] = nc;
    }
  }
}

extern "C" void kernel_launch(void* const* d_in, const int* in_sizes, int n_in,
                              void* d_out, int out_size, void* d_ws, size_t ws_size,
                              hipStream_t stream) {
  (void)in_sizes; (void)n_in; (void)out_size;
  const float* x        = (const float*)d_in[0];
  const float* m_prev   = (const float*)d_in[1];
  const float* c_prev   = (const float*)d_in[2];
  const float* w_m      = (const float*)d_in[3];
  const float* w_inputs = (const float*)d_in[4];
  float* out = (float*)d_out;

  // ws layout: [0,64MB) B tile images; then xh,xl,mh,ml (16MB each) = 128MB.
  if (ws_size >= 134217728ull && d_ws != nullptr) {
    u32* wsB = (u32*)d_ws;
    _Float16* xh = (_Float16*)((char*)d_ws + 67108864);
    _Float16* xl = xh + 8388608;
    _Float16* mh = xl + 8388608;
    _Float16* ml = mh + 8388608;
    prep_b<<<dim3(32, 64), 256, 0, stream>>>(w_inputs, w_m, wsB);
    split_a<<<4096, 256, 0, stream>>>((const float4v*)x, (half8*)xh, (half8*)xl);
    split_a<<<4096, 256, 0, stream>>>((const float4v*)m_prev, (half8*)mh, (half8*)ml);
    nascell_fast<<<dim3(64, 32), 256, 0, stream>>>(xh, xl, mh, ml, wsB, c_prev, out);
  } else {
    dim3 grid(64, 32);
    nascell_main<<<grid, 256, 0, stream>>>(x, m_prev, c_prev, w_inputs, w_m, out);
  }
}